// Round 3
// baseline (3793.906 us; speedup 1.0000x reference)
//
#include <hip/hip_runtime.h>
#include <hip/hip_bf16.h>

// ---------------------------------------------------------------------------
// AJ-RNN forward: 2-layer LSTM (B=128,T=256,D=64,H=512) with missing-value
// imputation (MISSING=128.0, pred = h2_{t-1} @ W + bias).
// Round 3: float32 I/O (per reference dtypes), bf16 MFMA internals, fp32 cell
// state, prediction rows streamed to d_out during the recurrence.
// ---------------------------------------------------------------------------

typedef __bf16  v8bf  __attribute__((ext_vector_type(8)));
typedef float   f32x4 __attribute__((ext_vector_type(4)));

constexpr int B_ = 128, T_ = 256, D_ = 64, H_ = 512;

// workspace layout (bytes, 256-aligned)
constexpr size_t OFF_WP1 = 0;        // packed [k0;r0] bf16 -> 2359296 B
constexpr size_t OFF_WP2 = 2359296;  // packed [k1;r1] bf16 -> 4194304 B
constexpr size_t OFF_WPP = 6553600;  // packed W bf16       ->   65536 B
constexpr size_t OFF_H1A = 6619136;  // h1 ping bf16           131072 B
constexpr size_t OFF_H1B = 6750208;  // h1 pong bf16           131072 B
constexpr size_t OFF_H2A = 6881280;  // h2 ping bf16           131072 B
constexpr size_t OFF_H2B = 7012352;  // h2 pong bf16           131072 B
constexpr size_t OFF_C1  = 7143424;  // c1 f32                 262144 B
constexpr size_t OFF_C2  = 7405568;  // c2 f32                 262144 B
// total 7667712 B (~7.3 MB)

__device__ __forceinline__ v8bf ldv(const __hip_bfloat16* p) {
  return *reinterpret_cast<const v8bf*>(p);
}
__device__ __forceinline__ float sigf(float x) { return 1.0f / (1.0f + __expf(-x)); }
__device__ __forceinline__ float tanhfast(float x) {
  x = fminf(15.0f, fmaxf(-15.0f, x));
  float e = __expf(-2.0f * x);
  return (1.0f - e) / (1.0f + e);
}

// ---------------------------------------------------------------------------
// Pack B-operand fragments (float32 in, bf16 out):
// out[((ct*nkc + kc)*64 + lane)*8 + j] = Wcat[kc*32 + (lane>>4)*8 + j][ct*16 + (lane&15)]
// Wcat = [kp (krows rows) ; rp] row-major, ncols columns. One 16B fragment
// per (col-tile, k-chunk, lane) -> a single dwordx4 load in the GEMM loops.
// ---------------------------------------------------------------------------
__global__ __launch_bounds__(256) void pack_weights(
    const float* __restrict__ kp, const float* __restrict__ rp,
    int krows, int ncols, int nkc, int nct, __hip_bfloat16* __restrict__ out) {
  int tid = blockIdx.x * 256 + threadIdx.x;
  int total = nct * nkc * 64;
  if (tid >= total) return;
  int L  = tid & 63;
  int kc = (tid >> 6) % nkc;
  int ct = tid / (64 * nkc);
  int n  = ct * 16 + (L & 15);
  int kb = kc * 32 + (L >> 4) * 8;
  __hip_bfloat16* dst = out + (size_t)tid * 8;
#pragma unroll
  for (int j = 0; j < 8; ++j) {
    int kk = kb + j;
    float v = (kk < krows) ? kp[kk * ncols + n] : rp[(kk - krows) * ncols + n];
    dst[j] = __float2bfloat16(v);
  }
}

// zero c1, c2, h1 ping, h2 ping (ws is re-poisoned to 0xAA before every call)
__global__ __launch_bounds__(256) void init_state(
    float* __restrict__ c1, float* __restrict__ c2,
    __hip_bfloat16* __restrict__ h1a, __hip_bfloat16* __restrict__ h2a) {
  int idx = blockIdx.x * 256 + threadIdx.x;   // 65536 total
  c1[idx] = 0.0f;
  c2[idx] = 0.0f;
  h1a[idx] = __float2bfloat16(0.0f);
  h2a[idx] = __float2bfloat16(0.0f);
}

// ---------------------------------------------------------------------------
// Layer-1 step. Block = (rg,cg): 16 batch rows x 16 h-cols, 4 waves (1/gate).
// Phase 1 (t>0): pred[16,64] = h2_{t-1} @ W + bias  (K=512; cg==0 block also
//                streams this tile to d_out as float32 prediction rows (b,t-1))
// Phase 2: cur = (t>0 && x==128.0f) ? pred : x      (bf16 in LDS)
// Phase 3: z tile = [cur | h1_{t-1}] @ Wcat1        (K=576)
// Phase 4: gates -> c1 (f32), h1_t (bf16 ping-pong)
// ---------------------------------------------------------------------------
__global__ __launch_bounds__(256) void step_l1(
    const float* __restrict__ x,
    const __hip_bfloat16* __restrict__ Wp1,
    const __hip_bfloat16* __restrict__ WpP,
    const float* __restrict__ b0,
    const float* __restrict__ biasD,
    const __hip_bfloat16* __restrict__ h2r,
    const __hip_bfloat16* __restrict__ h1r,
    __hip_bfloat16* __restrict__ h1w,
    float* __restrict__ c1,
    float* __restrict__ pred_out,   // d_out prediction region (float32)
    int t) {
  __shared__ __hip_bfloat16 curL[16][72];
  __shared__ float predb[16][68];
  __shared__ float zb[4][16][16];

  const int rg = blockIdx.x >> 5;
  const int cg = blockIdx.x & 31;
  const int w  = threadIdx.x >> 6;
  const int L  = threadIdx.x & 63;
  const int m  = L & 15;
  const int q  = L >> 4;

  // ---- Phase 1: pred tile (cols w*16..w*16+16), K=512 over h2_{t-1} ----
  if (t > 0) {
    f32x4 acc = {0.f, 0.f, 0.f, 0.f};
    const int arow = (rg * 16 + m) * H_;
#pragma unroll
    for (int kc = 0; kc < 16; ++kc) {
      v8bf a  = ldv(h2r + arow + kc * 32 + q * 8);
      v8bf bb = ldv(WpP + ((w * 16 + kc) * 64 + L) * 8);
      acc = __builtin_amdgcn_mfma_f32_16x16x32_bf16(a, bb, acc, 0, 0, 0);
    }
    float bv = biasD[w * 16 + m];
#pragma unroll
    for (int r = 0; r < 4; ++r) predb[q * 4 + r][w * 16 + m] = acc[r] + bv;
  }
  __syncthreads();

  // ---- Phase 2: build cur (bf16) in LDS; cg==0 streams pred -> d_out ----
  {
    int row = threadIdx.x >> 4;
    int c0  = (threadIdx.x & 15) * 4;
    int R   = rg * 16 + row;
#pragma unroll
    for (int j = 0; j < 4; ++j) {
      int c = c0 + j;
      float xf = x[(R * T_ + t) * D_ + c];
      bool missv = (t > 0) && (xf == 128.0f);
      curL[row][c] = __float2bfloat16(missv ? predb[row][c] : xf);
    }
    if (cg == 0 && t > 0) {
      size_t orow = ((size_t)R * (T_ - 1) + (t - 1)) * D_;
#pragma unroll
      for (int j = 0; j < 4; ++j)
        pred_out[orow + c0 + j] = predb[row][c0 + j];
    }
  }
  __syncthreads();

  // ---- Phase 3: z tile for gate w, K = 64 (cur) + 512 (h1_{t-1}) ----
  f32x4 z = {0.f, 0.f, 0.f, 0.f};
  {
    const int ct = w * 32 + cg;
    const int h1row = (rg * 16 + m) * H_;
#pragma unroll
    for (int kc = 0; kc < 18; ++kc) {
      v8bf a;
      if (kc < 2) a = ldv(&curL[m][kc * 32 + q * 8]);
      else        a = ldv(h1r + h1row + (kc - 2) * 32 + q * 8);
      v8bf bb = ldv(Wp1 + ((ct * 18 + kc) * 64 + L) * 8);
      z = __builtin_amdgcn_mfma_f32_16x16x32_bf16(a, bb, z, 0, 0, 0);
    }
  }
#pragma unroll
  for (int r = 0; r < 4; ++r) zb[w][q * 4 + r][m] = z[r];
  __syncthreads();

  // ---- Phase 4: gates + state update ----
  {
    int row = threadIdx.x >> 4;
    int col = threadIdx.x & 15;
    int C = cg * 16 + col;
    float iv = zb[0][row][col] + b0[C];
    float fv = zb[1][row][col] + b0[512 + C];
    float gv = zb[2][row][col] + b0[1024 + C];
    float ov = zb[3][row][col] + b0[1536 + C];
    float ig = sigf(iv), fg = sigf(fv), gg = tanhfast(gv), og = sigf(ov);
    int R = rg * 16 + row;
    float cold = c1[R * H_ + C];
    float cn = fg * cold + ig * gg;
    float hn = og * tanhfast(cn);
    c1[R * H_ + C] = cn;
    h1w[R * H_ + C] = __float2bfloat16(hn);
  }
}

// ---------------------------------------------------------------------------
// Layer-2 step: z = [h1_t | h2_{t-1}] @ Wcat2 (K=1024) -> c2 (f32), h2_t.
// At t==T-1 also writes last_cell region of d_out (float32).
// ---------------------------------------------------------------------------
__global__ __launch_bounds__(256) void step_l2(
    const __hip_bfloat16* __restrict__ Wp2,
    const float* __restrict__ b1,
    const __hip_bfloat16* __restrict__ h2r,
    __hip_bfloat16* __restrict__ h2w,
    const __hip_bfloat16* __restrict__ h1w,
    float* __restrict__ c2,
    float* __restrict__ last_out,   // d_out last_cell region (float32)
    int t) {
  __shared__ float zb[4][16][16];

  const int rg = blockIdx.x >> 5;
  const int cg = blockIdx.x & 31;
  const int w  = threadIdx.x >> 6;
  const int L  = threadIdx.x & 63;
  const int m  = L & 15;
  const int q  = L >> 4;

  f32x4 z = {0.f, 0.f, 0.f, 0.f};
  {
    const int ct = w * 32 + cg;
    const int arow = (rg * 16 + m) * H_;
#pragma unroll
    for (int kc = 0; kc < 32; ++kc) {
      v8bf a = (kc < 16) ? ldv(h1w + arow + kc * 32 + q * 8)
                         : ldv(h2r + arow + (kc - 16) * 32 + q * 8);
      v8bf bb = ldv(Wp2 + ((ct * 32 + kc) * 64 + L) * 8);
      z = __builtin_amdgcn_mfma_f32_16x16x32_bf16(a, bb, z, 0, 0, 0);
    }
  }
#pragma unroll
  for (int r = 0; r < 4; ++r) zb[w][q * 4 + r][m] = z[r];
  __syncthreads();

  {
    int row = threadIdx.x >> 4;
    int col = threadIdx.x & 15;
    int C = cg * 16 + col;
    float iv = zb[0][row][col] + b1[C];
    float fv = zb[1][row][col] + b1[512 + C];
    float gv = zb[2][row][col] + b1[1024 + C];
    float ov = zb[3][row][col] + b1[1536 + C];
    float ig = sigf(iv), fg = sigf(fv), gg = tanhfast(gv), og = sigf(ov);
    int R = rg * 16 + row;
    float cold = c2[R * H_ + C];
    float cn = fg * cold + ig * gg;
    float hn = og * tanhfast(cn);
    c2[R * H_ + C] = cn;
    h2w[R * H_ + C] = __float2bfloat16(hn);
    if (t == T_ - 1) last_out[R * H_ + C] = hn;
  }
}

// ---------------------------------------------------------------------------
extern "C" void kernel_launch(void* const* d_in, const int* in_sizes, int n_in,
                              void* d_out, int out_size, void* d_ws, size_t ws_size,
                              hipStream_t stream) {
  const float* x    = (const float*)d_in[0];
  const float* k0   = (const float*)d_in[1];
  const float* r0   = (const float*)d_in[2];
  const float* b0   = (const float*)d_in[3];
  const float* k1   = (const float*)d_in[4];
  const float* r1   = (const float*)d_in[5];
  const float* b1   = (const float*)d_in[6];
  const float* W    = (const float*)d_in[7];
  const float* bias = (const float*)d_in[8];

  char* ws = (char*)d_ws;
  __hip_bfloat16* Wp1 = (__hip_bfloat16*)(ws + OFF_WP1);
  __hip_bfloat16* Wp2 = (__hip_bfloat16*)(ws + OFF_WP2);
  __hip_bfloat16* WpP = (__hip_bfloat16*)(ws + OFF_WPP);
  __hip_bfloat16* h1a = (__hip_bfloat16*)(ws + OFF_H1A);
  __hip_bfloat16* h1b = (__hip_bfloat16*)(ws + OFF_H1B);
  __hip_bfloat16* h2a = (__hip_bfloat16*)(ws + OFF_H2A);
  __hip_bfloat16* h2b = (__hip_bfloat16*)(ws + OFF_H2B);
  float*          c1  = (float*)(ws + OFF_C1);
  float*          c2  = (float*)(ws + OFF_C2);

  pack_weights<<<(128 * 18 * 64 + 255) / 256, 256, 0, stream>>>(k0, r0, 64, 2048, 18, 128, Wp1);
  pack_weights<<<(128 * 32 * 64 + 255) / 256, 256, 0, stream>>>(k1, r1, 512, 2048, 32, 128, Wp2);
  pack_weights<<<(4 * 16 * 64 + 255) / 256, 256, 0, stream>>>(W, W, 512, 64, 16, 4, WpP);
  init_state<<<256, 256, 0, stream>>>(c1, c2, h1a, h2a);

  float* outp = (float*)d_out;
  float* last = outp + (size_t)B_ * (T_ - 1) * D_;

  for (int t = 0; t < T_; ++t) {
    const __hip_bfloat16* h1r = (t & 1) ? h1b : h1a;
    __hip_bfloat16*       h1w = (t & 1) ? h1a : h1b;
    const __hip_bfloat16* h2r = (t & 1) ? h2b : h2a;
    __hip_bfloat16*       h2w = (t & 1) ? h2a : h2b;
    step_l1<<<256, 256, 0, stream>>>(x, Wp1, WpP, b0, bias, h2r, h1r, h1w, c1, outp, t);
    step_l2<<<256, 256, 0, stream>>>(Wp2, b1, h2r, h2w, h1w, c2, last, t);
  }
}